// Round 1
// baseline (265.880 us; speedup 1.0000x reference)
//
#include <hip/hip_runtime.h>
#include <math.h>

// Problem constants (from setup_inputs)
#define T_TOTAL 2097152
#define A_DIM   18
#define GAMMA_D 0.99

// Scan blocking
#define CHUNK 256
#define NC    (T_TOTAL / CHUNK)   // 8192 chunks
#define KTR   14                  // carry truncation: G^14 ~ 2e-16

// Main pass
#define ROWS_PER_TILE 256
#define NTILES  (T_TOTAL / ROWS_PER_TILE)  // 8192
#define NB_MAIN 2048

// ---------------------------------------------------------------------------
// Kernel A: per-chunk local discounted sums  L_c = sum_{j=0}^{255} g^j r[s+j]
// 4-way split to shorten the dependent f64 FMA chain (64 iters instead of 256).
__global__ void k_local(const float* __restrict__ r, double* __restrict__ L) {
    int c = blockIdx.x * blockDim.x + threadIdx.x;
    const float4* r4 = (const float4*)(r + (size_t)c * CHUNK);
    const double g  = GAMMA_D;
    const double g4 = g * g * g * g;
    double a0 = 0.0, a1 = 0.0, a2 = 0.0, a3 = 0.0;
    for (int k = CHUNK / 4 - 1; k >= 0; --k) {
        float4 v = r4[k];
        a0 = a0 * g4 + (double)v.x;
        a1 = a1 * g4 + (double)v.y;
        a2 = a2 * g4 + (double)v.z;
        a3 = a3 * g4 + (double)v.w;
    }
    L[c] = a0 + g * (a1 + g * (a2 + g * a3));
}

// ---------------------------------------------------------------------------
// Kernel B: carry_in[c] = d at start of chunk c+1 = sum_{m>=0} G^m L[c+1+m].
// G = 0.99^256 ~ 0.076 so 14 terms reach double precision — fully parallel.
__global__ void k_carry(const double* __restrict__ L, double* __restrict__ carry,
                        double G) {
    int c = blockIdx.x * blockDim.x + threadIdx.x;
    double acc = 0.0;
    double w = 1.0;
    for (int m = 0; m < KTR; ++m) {
        int idx = c + 1 + m;
        if (idx < NC) acc += w * L[idx];
        w *= G;
    }
    carry[c] = acc;
}

// ---------------------------------------------------------------------------
// Kernel C: expand each chunk: d[t] = r[t] + g*d[t+1], seeded by carry_in.
__global__ void k_expand(const float* __restrict__ r,
                         const double* __restrict__ carry,
                         float* __restrict__ d) {
    int c = blockIdx.x * blockDim.x + threadIdx.x;
    const float4* r4 = (const float4*)(r + (size_t)c * CHUNK);
    float4*       d4 = (float4*)(d + (size_t)c * CHUNK);
    const double g = GAMMA_D;
    double cur = carry[c];
    for (int k = CHUNK / 4 - 1; k >= 0; --k) {
        float4 v = r4[k];
        double e3 = cur * g + (double)v.w;
        double e2 = e3 * g + (double)v.z;
        double e1 = e2 * g + (double)v.y;
        double e0 = e1 * g + (double)v.x;
        d4[k] = make_float4((float)e0, (float)e1, (float)e2, (float)e3);
        cur = e0;
    }
}

// ---------------------------------------------------------------------------
// Kernel D: main pass. LDS-staged coalesced weight reads; per-row logsumexp;
// double partial sums per block (no atomics, no ws zero-init needed).
__launch_bounds__(256)
__global__ void k_main(const float* __restrict__ w, const int* __restrict__ act,
                       const float* __restrict__ d, double* __restrict__ partials) {
    __shared__ float  lds[ROWS_PER_TILE * A_DIM];   // 4608 floats = 18 KiB
    __shared__ double red[12];
    const int tid = threadIdx.x;
    double s_d = 0.0, s_n = 0.0, s_nd = 0.0;

    for (int tile = blockIdx.x; tile < NTILES; tile += gridDim.x) {
        const float4* src = (const float4*)(w + (size_t)tile * ROWS_PER_TILE * A_DIM);
        float4* dst = (float4*)lds;
        __syncthreads();   // protect lds from previous tile's readers
        for (int idx = tid; idx < ROWS_PER_TILE * A_DIM / 4; idx += 256)
            dst[idx] = src[idx];
        __syncthreads();

        const int row = tile * ROWS_PER_TILE + tid;
        const float* wr = lds + tid * A_DIM;
        float m = wr[0];
        #pragma unroll
        for (int j = 1; j < A_DIM; ++j) m = fmaxf(m, wr[j]);
        float s = 0.0f;
        #pragma unroll
        for (int j = 0; j < A_DIM; ++j) s += expf(wr[j] - m);
        float lse  = m + logf(s);
        float nlp  = lse - wr[act[row]];
        float dv   = d[row];
        s_d  += (double)dv;
        s_n  += (double)nlp;
        s_nd += (double)nlp * (double)dv;
    }

    // wave (64-lane) shuffle reduction, then cross-wave via LDS
    for (int off = 32; off > 0; off >>= 1) {
        s_d  += __shfl_down(s_d,  off, 64);
        s_n  += __shfl_down(s_n,  off, 64);
        s_nd += __shfl_down(s_nd, off, 64);
    }
    const int lane = tid & 63, wv = tid >> 6;
    if (lane == 0) { red[wv*3+0] = s_d; red[wv*3+1] = s_n; red[wv*3+2] = s_nd; }
    __syncthreads();
    if (tid == 0) {
        double a = 0.0, b = 0.0, c = 0.0;
        for (int i = 0; i < 4; ++i) { a += red[i*3]; b += red[i*3+1]; c += red[i*3+2]; }
        partials[blockIdx.x*3+0] = a;
        partials[blockIdx.x*3+1] = b;
        partials[blockIdx.x*3+2] = c;
    }
}

// ---------------------------------------------------------------------------
// Kernel E: reduce per-block partials, finalize scalar.
__global__ void k_final(const double* __restrict__ partials, float* __restrict__ out) {
    __shared__ double red[12];
    const int tid = threadIdx.x;
    double a = 0.0, b = 0.0, c = 0.0;
    for (int i = tid; i < NB_MAIN; i += 256) {
        a += partials[i*3+0];
        b += partials[i*3+1];
        c += partials[i*3+2];
    }
    for (int off = 32; off > 0; off >>= 1) {
        a += __shfl_down(a, off, 64);
        b += __shfl_down(b, off, 64);
        c += __shfl_down(c, off, 64);
    }
    const int lane = tid & 63, wv = tid >> 6;
    if (lane == 0) { red[wv*3+0] = a; red[wv*3+1] = b; red[wv*3+2] = c; }
    __syncthreads();
    if (tid == 0) {
        double A_ = 0.0, B_ = 0.0, C_ = 0.0;
        for (int i = 0; i < 4; ++i) { A_ += red[i*3]; B_ += red[i*3+1]; C_ += red[i*3+2]; }
        const double invT = 1.0 / (double)T_TOTAL;
        // out = (1/T) * ( sum(nlp*d) - mean(d) * sum(nlp) )
        double res = (C_ - (A_ * invT) * B_) * invT;
        out[0] = (float)res;
    }
}

// ---------------------------------------------------------------------------
extern "C" void kernel_launch(void* const* d_in, const int* in_sizes, int n_in,
                              void* d_out, int out_size, void* d_ws, size_t ws_size,
                              hipStream_t stream) {
    const float* weight = (const float*)d_in[0];   // [T, 18] f32
    const float* ep_rs  = (const float*)d_in[1];   // [T] f32
    const int*   ep_as  = (const int*)  d_in[2];   // [T] int
    float* out = (float*)d_out;

    char* ws = (char*)d_ws;
    double* L        = (double*)(ws);                    // NC doubles   (64 KiB)
    double* carry    = (double*)(ws + (1  << 16));       // NC doubles   (64 KiB)
    double* partials = (double*)(ws + (2  << 16));       // NB_MAIN*3 doubles (48 KiB)
    float*  d        = (float*) (ws + (3  << 16));       // T floats     (8 MiB)

    const double G = pow(GAMMA_D, (double)CHUNK);

    k_local <<<NC / 256, 256, 0, stream>>>(ep_rs, L);
    k_carry <<<NC / 256, 256, 0, stream>>>(L, carry, G);
    k_expand<<<NC / 256, 256, 0, stream>>>(ep_rs, carry, d);
    k_main  <<<NB_MAIN,  256, 0, stream>>>(weight, ep_as, d, partials);
    k_final <<<1,        256, 0, stream>>>(partials, out);
}

// Round 2
// 234.174 us; speedup vs baseline: 1.1354x; 1.1354x over previous
//
#include <hip/hip_runtime.h>
#include <math.h>

// Problem constants (from setup_inputs)
#define T_TOTAL 2097152
#define A_DIM   18
#define GAMMA_D 0.99

// Scan blocking: chunk == main-pass tile == block size
#define CHUNK 256
#define NC    (T_TOTAL / CHUNK)        // 8192 chunks
#define KTR   14                       // G^14 ~ 2e-16, G = 0.99^256 ~ 0.076

#define NB_MAIN 2048                   // main-kernel blocks (4 chunks each)

// ---------------------------------------------------------------------------
// Kernel A: per-chunk local discounted sums, one WAVE per chunk (full chip).
// L[c] = sum_{j=0}^{255} g^j r[c*256+j]; lane handles 4 consecutive floats.
__global__ void k_local(const float* __restrict__ r, double* __restrict__ L) {
    const int tid  = blockIdx.x * blockDim.x + threadIdx.x;
    const int c    = tid >> 6;                 // global wave id == chunk id
    const int lane = tid & 63;
    const float4 v = ((const float4*)r)[(size_t)c * 64 + lane];
    const double g = GAMMA_D;
    double w = pow(g, (double)(4 * lane)) *
               ((double)v.x + g * ((double)v.y + g * ((double)v.z + g * (double)v.w)));
    #pragma unroll
    for (int off = 32; off > 0; off >>= 1) w += __shfl_down(w, off, 64);
    if (lane == 0) L[c] = w;
}

// ---------------------------------------------------------------------------
// Kernel B: carry[c] = d at start of chunk c+1 = sum_{m=0}^{13} G^m L[c+1+m].
// L is 64 KiB -> L2-resident; fully parallel.
__global__ void k_carry(const double* __restrict__ L, double* __restrict__ carry,
                        double G) {
    const int c = blockIdx.x * blockDim.x + threadIdx.x;
    double acc = 0.0, w = 1.0;
    #pragma unroll
    for (int m = 0; m < KTR; ++m) {
        int idx = c + 1 + m;
        if (idx < NC) acc += w * L[idx];
        w *= G;
    }
    carry[c] = acc;
}

// ---------------------------------------------------------------------------
// Kernel C (fused main): per chunk of 256 rows —
//   - stage 18 KiB weight tile to LDS (coalesced float4)
//   - compute d[t] via in-block suffix scan (double):
//       w_pos = g^pos * r[t];  ss = wave suffix-sum;  tail = later-wave totals;
//       d = g^{-pos} * (ss + tail + g^256 * carry[c])
//   - f32 logsumexp per row, accumulate {sum d, sum nlp, sum nlp*d} in double.
__launch_bounds__(256)
__global__ void k_main(const float* __restrict__ wgt, const int* __restrict__ act,
                       const float* __restrict__ r, const double* __restrict__ carry,
                       double* __restrict__ partials) {
    __shared__ float  lds[CHUNK * A_DIM];     // 18 KiB
    __shared__ double ldsT[4];                // per-wave scan totals
    __shared__ double red[12];
    const int tid  = threadIdx.x;
    const int lane = tid & 63, wv = tid >> 6;
    const double g    = GAMMA_D;
    const double p    = pow(g, (double)tid);   // g^pos (pos fixed per thread)
    const double ip   = 1.0 / p;               // g^-pos  (<= ~13.0, safe)
    const double g256 = pow(g, 256.0);
    double s_d = 0.0, s_n = 0.0, s_nd = 0.0;

    for (int c = blockIdx.x; c < NC; c += gridDim.x) {
        __syncthreads();                      // protect LDS from prev iteration
        // ---- stage weight tile ----
        const float4* src = (const float4*)(wgt + (size_t)c * CHUNK * A_DIM);
        float4* dst = (float4*)lds;
        #pragma unroll
        for (int i = 0; i < 5; ++i) {
            int idx = tid + 256 * i;
            if (idx < CHUNK * A_DIM / 4) dst[idx] = src[idx];
        }
        // ---- suffix scan for d ----
        const int row = c * CHUNK + tid;
        double ss = p * (double)r[row];
        #pragma unroll
        for (int off = 1; off < 64; off <<= 1) {
            double v = __shfl_down(ss, off, 64);
            ss += (lane + off < 64) ? v : 0.0;
        }
        if (lane == 0) ldsT[wv] = ss;         // wave total (globally scaled)
        __syncthreads();
        double tail = 0.0;
        #pragma unroll
        for (int m = 0; m < 4; ++m)
            if (m > wv) tail += ldsT[m];
        const double dval = ip * (ss + tail + g256 * carry[c]);
        // ---- f32 logsumexp (matches reference dtype) ----
        const float* wr = lds + tid * A_DIM;
        float mx = wr[0];
        #pragma unroll
        for (int j = 1; j < A_DIM; ++j) mx = fmaxf(mx, wr[j]);
        float s = 0.0f;
        #pragma unroll
        for (int j = 0; j < A_DIM; ++j) s += expf(wr[j] - mx);
        const float nlp = mx + logf(s) - wr[act[row]];
        s_d  += dval;
        s_n  += (double)nlp;
        s_nd += (double)nlp * dval;
    }

    // block reduction: 64-lane shuffles, then cross-wave via LDS
    #pragma unroll
    for (int off = 32; off > 0; off >>= 1) {
        s_d  += __shfl_down(s_d,  off, 64);
        s_n  += __shfl_down(s_n,  off, 64);
        s_nd += __shfl_down(s_nd, off, 64);
    }
    if (lane == 0) { red[wv*3+0] = s_d; red[wv*3+1] = s_n; red[wv*3+2] = s_nd; }
    __syncthreads();
    if (tid == 0) {
        double a = 0.0, b = 0.0, cc = 0.0;
        #pragma unroll
        for (int i = 0; i < 4; ++i) { a += red[i*3]; b += red[i*3+1]; cc += red[i*3+2]; }
        partials[blockIdx.x*3+0] = a;
        partials[blockIdx.x*3+1] = b;
        partials[blockIdx.x*3+2] = cc;
    }
}

// ---------------------------------------------------------------------------
// Kernel D: reduce per-block partials, finalize scalar.
__global__ void k_final(const double* __restrict__ partials, float* __restrict__ out) {
    __shared__ double red[12];
    const int tid = threadIdx.x;
    double a = 0.0, b = 0.0, c = 0.0;
    for (int i = tid; i < NB_MAIN; i += 256) {
        a += partials[i*3+0];
        b += partials[i*3+1];
        c += partials[i*3+2];
    }
    #pragma unroll
    for (int off = 32; off > 0; off >>= 1) {
        a += __shfl_down(a, off, 64);
        b += __shfl_down(b, off, 64);
        c += __shfl_down(c, off, 64);
    }
    const int lane = tid & 63, wv = tid >> 6;
    if (lane == 0) { red[wv*3+0] = a; red[wv*3+1] = b; red[wv*3+2] = c; }
    __syncthreads();
    if (tid == 0) {
        double A_ = 0.0, B_ = 0.0, C_ = 0.0;
        #pragma unroll
        for (int i = 0; i < 4; ++i) { A_ += red[i*3]; B_ += red[i*3+1]; C_ += red[i*3+2]; }
        const double invT = 1.0 / (double)T_TOTAL;
        // out = (1/T) * ( sum(nlp*d) - mean(d) * sum(nlp) )
        out[0] = (float)((C_ - (A_ * invT) * B_) * invT);
    }
}

// ---------------------------------------------------------------------------
extern "C" void kernel_launch(void* const* d_in, const int* in_sizes, int n_in,
                              void* d_out, int out_size, void* d_ws, size_t ws_size,
                              hipStream_t stream) {
    const float* weight = (const float*)d_in[0];   // [T, 18] f32
    const float* ep_rs  = (const float*)d_in[1];   // [T] f32
    const int*   ep_as  = (const int*)  d_in[2];   // [T] int
    float* out = (float*)d_out;

    char* ws = (char*)d_ws;
    double* L        = (double*)(ws);               // NC doubles      (64 KiB)
    double* carry    = (double*)(ws + (1 << 16));   // NC doubles      (64 KiB)
    double* partials = (double*)(ws + (2 << 16));   // NB_MAIN*3 dbl   (48 KiB)

    const double G = pow(GAMMA_D, (double)CHUNK);

    k_local <<<T_TOTAL / 4 / 256, 256, 0, stream>>>(ep_rs, L);   // 2048 blocks
    k_carry <<<NC / 256,          256, 0, stream>>>(L, carry, G);
    k_main  <<<NB_MAIN,           256, 0, stream>>>(weight, ep_as, ep_rs, carry, partials);
    k_final <<<1,                 256, 0, stream>>>(partials, out);
}